// Round 6
// baseline (83.597 us; speedup 1.0000x reference)
//
#include <hip/hip_runtime.h>

// CorrelationAlign: out[b, a*63+c, i, j] = in[b, (a+i-31)*32 + (c+j-31), i, j]
//   valid iff 0 <= a+i-31 < 32 and 0 <= c+j-31 < 32, else 0.  b=16, h=w=32.
//
// R5: single-variable test vs R1 (58.8us): widen store spans 128B -> 1KB.
// Block = (b, a, i-group-of-8). 8 input tiles (4KB each) staged in LDS
// (skip loads for invalid p; store phase masks). Store: each c-row is
// 8i x 32j x 4B = 1KB CONTIGUOUS = one full wave float4-store instruction
// (vs R1's 8x128B comb at 4KB stride). Plain stores (R3 showed nt hurts).
// Per-tile LDS stride 1057 (=32*33+1): store-phase read bank =
// (isb + c + 2j) % 32 -> <=2-way aliasing (free, m136). LDS 33.8KB ->
// 4 blocks/CU x 4 waves = 16 waves/CU.

#define TSTR 1057   // per-i-subtile LDS stride (floats)

__global__ __launch_bounds__(256) void CorrelationAlign_kernel(
    const float* __restrict__ in, float* __restrict__ out) {
  __shared__ float tile[8 * TSTR];   // 33,824 B

  const int bid = blockIdx.x;        // ((b*63 + a) * 4 + g)
  const int g  = bid & 3;
  const int ba = bid >> 2;
  const int a  = ba % 63;
  const int b  = ba / 63;
  const int i0 = g * 8;
  const int t  = threadIdx.x;

  float* outbase = out + (size_t)(b * 3969 + a * 63) * 1024 + i0 * 32;
  const int plo = a + i0 - 31;       // p for isb = 0

  if (plo <= 31 && plo + 7 >= 0) {   // some tile valid (block-uniform)
    // ---- load phase: tile `it` is 32 rows x 128B, coalesced ----
    const int q  = t >> 3;           // 0..31
    const int j0 = (t & 7) * 4;      // 0,4,...,28
#pragma unroll
    for (int it = 0; it < 8; ++it) {
      const int p = plo + it;        // block-uniform branch
      if ((unsigned)p < 32u) {
        const float4 v = *reinterpret_cast<const float4*>(
            in + (size_t)(b * 1024 + p * 32 + q) * 1024 + (i0 + it) * 32 + j0);
        float* dst = &tile[it * TSTR + q * 33 + j0];
        dst[0] = v.x; dst[1] = v.y; dst[2] = v.z; dst[3] = v.w;
      }
    }
    __syncthreads();

    // ---- store phase: 63 c-rows, each 1KB contiguous (one wave-instr) ----
    for (int task = t; task < 63 * 64; task += 256) {
      const int c   = task >> 6;
      const int l   = task & 63;     // lane chunk within c-row
      const int isb = l >> 3;        // i sub-index 0..7
      const int js  = (l & 7) * 4;   // j0 within the i's 32 floats
      const int p   = plo + isb;
      const bool pv = (unsigned)p < 32u;
      float4 v;
      float* vp = reinterpret_cast<float*>(&v);
#pragma unroll
      for (int k = 0; k < 4; ++k) {
        const int j  = js + k;
        const int qq = c + j - 31;
        const int qc = min(max(qq, 0), 31);
        const float x = tile[isb * TSTR + qc * 33 + j];  // garbage ok if !pv
        vp[k] = (pv && (unsigned)qq < 32u) ? x : 0.0f;
      }
      *reinterpret_cast<float4*>(outbase + (size_t)c * 1024 + l * 4) = v;
    }
  } else {
    // ---- whole i-group invalid: pure zero-fill, 1KB contiguous rows ----
    const float4 z = make_float4(0.f, 0.f, 0.f, 0.f);
    for (int task = t; task < 63 * 64; task += 256) {
      const int c = task >> 6;
      const int l = task & 63;
      *reinterpret_cast<float4*>(outbase + (size_t)c * 1024 + l * 4) = z;
    }
  }
}

extern "C" void kernel_launch(void* const* d_in, const int* in_sizes, int n_in,
                              void* d_out, int out_size, void* d_ws,
                              size_t ws_size, hipStream_t stream) {
  (void)in_sizes; (void)n_in; (void)out_size; (void)d_ws; (void)ws_size;
  const float* in = (const float*)d_in[0];
  float* out = (float*)d_out;
  const int grid = 16 * 63 * 4;   // one block per (b, a, i-group-of-8)
  CorrelationAlign_kernel<<<grid, 256, 0, stream>>>(in, out);
}

// Round 7
// 60.282 us; speedup vs baseline: 1.3868x; 1.3868x over previous
//
#include <hip/hip_runtime.h>

// CorrelationAlign: out[b, a*63+c, i, j] = in[b, (a+i-31)*32 + (c+j-31), i, j]
//   valid iff 0 <= a+i-31 < 32 and 0 <= c+j-31 < 32, else 0.  b=16, h=w=32.
//
// R6: barrier-free wave-private tiles. Each WAVE owns one (b,a,i): loads its
// 32x32 input tile into a private 4.2KB LDS slice, then emits 63 c-rows.
// No __syncthreads anywhere -> no block-wide vmcnt(0) drain per tile; waves
// decouple (load-phase waves overlap store-phase waves, m114). 4 waves/block
// -> LDS 16.9KB -> 8 blocks/CU = 32 waves/CU (vs R1's barrier-synced 4-wave
// groups). Store comb (128B @ 4KB stride) kept: i-sibling waves co-dispatch
// and merge combs in time (R4/R5 showed "fixing" this only hurts).
// LDS stride 33: store-read bank = (c + 2j) % 32 -> 2-way aliasing (free).

#define WLDS (32 * 33)   // floats per wave slice = 4224 B

__global__ __launch_bounds__(256) void CorrelationAlign_kernel(
    const float* __restrict__ in, float* __restrict__ out) {
  __shared__ float lds[4 * WLDS];  // 16,896 B

  const int t    = threadIdx.x;
  const int w    = t >> 6;                    // wave 0..3
  const int lane = t & 63;
  const int gw   = blockIdx.x * 4 + w;        // ((b*63 + a) * 32 + i)
  const int i  = gw & 31;
  const int ba = gw >> 5;
  const int a  = ba % 63;
  const int b  = ba / 63;
  const int p  = a + i - 31;

  float* tile = &lds[w * WLDS];
  float* outbase = out + (size_t)(b * 3969 + a * 63) * 1024 + i * 32;

  const int rj0 = (lane & 7) * 4;             // j0 for this lane
  const int rq  = lane >> 3;                  // row sub-index 0..7

  if ((unsigned)p < 32u) {                    // wave-uniform branch
    // ---- load 32x32 tile: 4 wave-instrs, 8x128B coalesced each ----
    const float* inbase = in + (size_t)(b * 1024 + p * 32) * 1024 + i * 32;
#pragma unroll
    for (int r = 0; r < 4; ++r) {
      const int q = r * 8 + rq;
      const float4 v =
          *reinterpret_cast<const float4*>(inbase + (size_t)q * 1024 + rj0);
      float* dst = &tile[q * 33 + rj0];
      dst[0] = v.x; dst[1] = v.y; dst[2] = v.z; dst[3] = v.w;
    }
    // (wave-internal ds_write -> ds_read: compiler orders via lgkmcnt;
    //  no __syncthreads needed — each wave touches only its own slice)

    // ---- emit 63 c-rows: diagonal LDS read, coalesced float4 stores ----
#pragma unroll
    for (int s = 0; s < 8; ++s) {
      const int c = s * 8 + rq;
      if (c < 63) {
        float4 v;
        float* vp = reinterpret_cast<float*>(&v);
#pragma unroll
        for (int k = 0; k < 4; ++k) {
          const int j  = rj0 + k;
          const int q  = c + j - 31;
          const int qc = min(max(q, 0), 31);
          const float x = tile[qc * 33 + j];
          vp[k] = ((unsigned)q < 32u) ? x : 0.0f;
        }
        *reinterpret_cast<float4*>(outbase + (size_t)c * 1024 + rj0) = v;
      }
    }
  } else {
    // ---- whole (c, j) plane zero for this (b, a, i) ----
    const float4 z = make_float4(0.f, 0.f, 0.f, 0.f);
#pragma unroll
    for (int s = 0; s < 8; ++s) {
      const int c = s * 8 + rq;
      if (c < 63)
        *reinterpret_cast<float4*>(outbase + (size_t)c * 1024 + rj0) = z;
    }
  }
}

extern "C" void kernel_launch(void* const* d_in, const int* in_sizes, int n_in,
                              void* d_out, int out_size, void* d_ws,
                              size_t ws_size, hipStream_t stream) {
  (void)in_sizes; (void)n_in; (void)out_size; (void)d_ws; (void)ws_size;
  const float* in = (const float*)d_in[0];
  float* out = (float*)d_out;
  const int grid = 16 * 63 * 32 / 4;  // one wave per (b, a, i); 4 waves/block
  CorrelationAlign_kernel<<<grid, 256, 0, stream>>>(in, out);
}